// Round 17
// baseline (21.243 us; speedup 1.0000x reference)
//
#include <hip/hip_runtime.h>

#define F 8
#define L 16
#define XN 8
#define YN 4
#define BLK 256
#define NXCD 8

typedef float f32x4 __attribute__((ext_vector_type(4)));

// out layout: [L*N] (norm.T) followed by [YN*N] (out.T)
// R17 = R16 + (a) per-sample loads issued BEFORE table build (cold HBM latency
// hides under prologue), (b) single-barrier prologue: 16 threads build their
// own l-column of A/B/C0 straight from global, no s_Cp, no second barrier.
__global__ __launch_bounds__(256) void eafnn_kernel(
    const float* __restrict__ inp,
    const float* __restrict__ x,
    const float* __restrict__ c,
    const float* __restrict__ b,
    const float* __restrict__ w,
    float* __restrict__ out,
    int n_total, int nwg)
{
    __shared__ __attribute__((aligned(16))) float s_A[F * L];
    __shared__ __attribute__((aligned(16))) float s_B[F * L];
    __shared__ __attribute__((aligned(16))) float s_C0[L];
    __shared__ __attribute__((aligned(16))) float s_norm[L][BLK];   // 16 KB
    __shared__ __attribute__((aligned(16))) float s_y[YN][BLK];     //  4 KB

    const int tid = threadIdx.x;

    // Bijective XCD-contiguous remap (m204).
    const int bid = (int)blockIdx.x;
    const int q = nwg / NXCD, r = nwg % NXCD;
    const int xcd = bid % NXCD, idx = bid / NXCD;
    const int blk = (xcd < r ? xcd * (q + 1) : r * (q + 1) + (xcd - r) * q) + idx;

    const size_t base_n = (size_t)blk * BLK;
    int n = (int)base_n + tid;
    if (n >= n_total) n = n_total - 1;   // clamp loads; stores quad-guarded below

    // ---- per-sample loads FIRST: latency hides under the table build ----
    const f32x4* ip = (const f32x4*)(inp + (size_t)n * F);
    f32x4 a0 = ip[0], a1 = ip[1];
    const f32x4* xp = (const f32x4*)(x + (size_t)n * XN);
    f32x4 x0 = xp[0], x1 = xp[1];

    // ---- one-barrier prologue: thread l (<16) builds its column of A/B/C0 ----
    // k*d^2 = A*v^2 + B*v + C,  A = k = -log2(e)/(2b^2), B = -2kc, C0[l] = sum_f k c^2
    if (tid < L) {
        float c0 = 0.0f;
#pragma unroll
        for (int f = 0; f < F; ++f) {
            float bb = b[f * L + tid];     // 16 lanes, consecutive addrs: coalesced
            float cc = c[f * L + tid];
            float k = -1.4426950408889634f / (2.0f * bb * bb);
            s_A[f * L + tid] = k;
            s_B[f * L + tid] = -2.0f * k * cc;
            c0 = fmaf(k * cc, cc, c0);
        }
        s_C0[tid] = c0;
    }
    __syncthreads();

    float fi[F] = {a0.x, a0.y, a0.z, a0.w, a1.x, a1.y, a1.z, a1.w};
    float xv[XN] = {x0.x, x0.y, x0.z, x0.w, x1.x, x1.y, x1.z, x1.w};

    // ---- membership accumulation in log2 domain (LDS tables) ----
    float sacc[L];
#pragma unroll
    for (int lq = 0; lq < L / 4; ++lq) {
        f32x4 cq = *(const f32x4*)&s_C0[lq * 4];
        sacc[lq * 4 + 0] = cq.x;
        sacc[lq * 4 + 1] = cq.y;
        sacc[lq * 4 + 2] = cq.z;
        sacc[lq * 4 + 3] = cq.w;
    }

#pragma unroll
    for (int f = 0; f < F; ++f) {
        float v = fi[f];
        float v2 = v * v;
#pragma unroll
        for (int lq = 0; lq < L / 4; ++lq) {
            f32x4 Aq = *(const f32x4*)&s_A[f * L + lq * 4];
            f32x4 Bq = *(const f32x4*)&s_B[f * L + lq * 4];
            sacc[lq * 4 + 0] = fmaf(Aq.x, v2, fmaf(Bq.x, v, sacc[lq * 4 + 0]));
            sacc[lq * 4 + 1] = fmaf(Aq.y, v2, fmaf(Bq.y, v, sacc[lq * 4 + 1]));
            sacc[lq * 4 + 2] = fmaf(Aq.z, v2, fmaf(Bq.z, v, sacc[lq * 4 + 2]));
            sacc[lq * 4 + 3] = fmaf(Aq.w, v2, fmaf(Bq.w, v, sacc[lq * 4 + 3]));
        }
    }

    // ---- firing + normalization -> LDS ----
    float tot = 0.0f;
#pragma unroll
    for (int l = 0; l < L; ++l) {
        float fr = __builtin_amdgcn_exp2f(sacc[l]) + 0.001f;
        sacc[l] = fr;
        tot += fr;
    }
    float inv = __builtin_amdgcn_rcpf(tot);
#pragma unroll
    for (int l = 0; l < L; ++l) {
        float nl = sacc[l] * inv;
        sacc[l] = nl;                    // keep norm for consequents
        s_norm[l][tid] = nl;
    }

    // ---- consequents: w via wave-uniform global loads -> LDS ----
    float acc[YN] = {0.f, 0.f, 0.f, 0.f};
#pragma unroll
    for (int l = 0; l < L; ++l) {
        float t0 = 0.f, t1 = 0.f, t2 = 0.f, t3 = 0.f;
#pragma unroll
        for (int i = 0; i < XN; ++i) {
            f32x4 wq = *(const f32x4*)&w[(l * XN + i) * YN];  // uniform addr
            float xs = xv[i];
            t0 = fmaf(xs, wq.x, t0);
            t1 = fmaf(xs, wq.y, t1);
            t2 = fmaf(xs, wq.z, t2);
            t3 = fmaf(xs, wq.w, t3);
        }
        float nl = sacc[l];
        acc[0] = fmaf(nl, t0, acc[0]);
        acc[1] = fmaf(nl, t1, acc[1]);
        acc[2] = fmaf(nl, t2, acc[2]);
        acc[3] = fmaf(nl, t3, acc[3]);
    }
#pragma unroll
    for (int y = 0; y < YN; ++y) s_y[y][tid] = acc[y];

    __syncthreads();

    // ---- store phase: 16B/lane NT stores, 4 KB contiguous per wave-store ----
    const int ww = tid >> 6, lane = tid & 63;
    const size_t nidx = base_n + (size_t)lane * 4;
    const bool qok = (nidx + 3) < (size_t)n_total;   // n_total%4==0 -> exact guard

#pragma unroll
    for (int rr = 0; rr < 4; ++rr) {
        int row = ww * 4 + rr;
        f32x4 v = *(const f32x4*)&s_norm[row][lane * 4];
        if (qok)
            __builtin_nontemporal_store(v, (f32x4*)&out[(size_t)row * n_total + nidx]);
    }
    {
        f32x4 v = *(const f32x4*)&s_y[ww][lane * 4];   // ww < 4 == YN
        float* out_y = out + (size_t)L * n_total;
        if (qok)
            __builtin_nontemporal_store(v, (f32x4*)&out_y[(size_t)ww * n_total + nidx]);
    }
}

extern "C" void kernel_launch(void* const* d_in, const int* in_sizes, int n_in,
                              void* d_out, int out_size, void* d_ws, size_t ws_size,
                              hipStream_t stream) {
    const float* inp = (const float*)d_in[0];
    const float* x   = (const float*)d_in[1];
    const float* c   = (const float*)d_in[2];
    const float* b   = (const float*)d_in[3];
    const float* w   = (const float*)d_in[4];
    float* out = (float*)d_out;

    int n_total = in_sizes[0] / F;   // 500000
    int grid = (n_total + BLK - 1) / BLK;
    eafnn_kernel<<<grid, BLK, 0, stream>>>(inp, x, c, b, w, out, n_total, grid);
}

// Round 18
// 20.114 us; speedup vs baseline: 1.0561x; 1.0561x over previous
//
#include <hip/hip_runtime.h>

#define F 8
#define L 16
#define XN 8
#define YN 4
#define BLK 256
#define NXCD 8

typedef float f32x4 __attribute__((ext_vector_type(4)));

// out layout: [L*N] (norm.T) followed by [YN*N] (out.T)
// R18 = exact revert to R16 (best: 20.23 us).
// R16 = R14 + bijective XCD-contiguous block swizzle; outputs staged in LDS,
// block-transposed, stored as 16B/lane NT dwordx4 (4KB contiguous per wave-store).
// Ledger: NS-batching/occupancy-caps/fences/persistence/prologue-restructure all
// regress; NT stores (+1.1us), LDS-transpose stores (+0.6us), XCD swizzle (+0.35us).
__global__ __launch_bounds__(256) void eafnn_kernel(
    const float* __restrict__ inp,
    const float* __restrict__ x,
    const float* __restrict__ c,
    const float* __restrict__ b,
    const float* __restrict__ w,
    float* __restrict__ out,
    int n_total, int nwg)
{
    // k*d^2 = A*v^2 + B*v + C,  A = k = -log2(e)/(2b^2), B = -2kc, C0[l] = sum_f k c^2
    __shared__ __attribute__((aligned(16))) float s_A[F * L];
    __shared__ __attribute__((aligned(16))) float s_B[F * L];
    __shared__ __attribute__((aligned(16))) float s_Cp[F * L];
    __shared__ __attribute__((aligned(16))) float s_C0[L];
    __shared__ __attribute__((aligned(16))) float s_norm[L][BLK];   // 16 KB
    __shared__ __attribute__((aligned(16))) float s_y[YN][BLK];     //  4 KB

    const int tid = threadIdx.x;
    if (tid < F * L) {
        float bb = b[tid], cc = c[tid];
        float k = -1.4426950408889634f / (2.0f * bb * bb);
        s_A[tid] = k;
        s_B[tid] = -2.0f * k * cc;
        s_Cp[tid] = k * cc * cc;
    }
    __syncthreads();
    if (tid < L) {
        float a = 0.0f;
#pragma unroll
        for (int f = 0; f < F; ++f) a += s_Cp[f * L + tid];
        s_C0[tid] = a;
    }
    __syncthreads();

    // Bijective XCD-contiguous remap (m204): dispatch round-robins blocks
    // across XCDs; remap so XCD k owns a contiguous chunk range.
    const int bid = (int)blockIdx.x;
    const int q = nwg / NXCD, r = nwg % NXCD;
    const int xcd = bid % NXCD, idx = bid / NXCD;
    const int blk = (xcd < r ? xcd * (q + 1) : r * (q + 1) + (xcd - r) * q) + idx;

    const size_t base_n = (size_t)blk * BLK;
    int n = (int)base_n + tid;
    if (n >= n_total) n = n_total - 1;   // clamp loads; stores quad-guarded below

    // ---- coalesced per-sample inputs ----
    const f32x4* ip = (const f32x4*)(inp + (size_t)n * F);
    f32x4 a0 = ip[0], a1 = ip[1];
    float fi[F] = {a0.x, a0.y, a0.z, a0.w, a1.x, a1.y, a1.z, a1.w};

    const f32x4* xp = (const f32x4*)(x + (size_t)n * XN);
    f32x4 x0 = xp[0], x1 = xp[1];
    float xv[XN] = {x0.x, x0.y, x0.z, x0.w, x1.x, x1.y, x1.z, x1.w};

    // ---- membership accumulation in log2 domain (LDS tables) ----
    float sacc[L];
#pragma unroll
    for (int lq = 0; lq < L / 4; ++lq) {
        f32x4 cq = *(const f32x4*)&s_C0[lq * 4];
        sacc[lq * 4 + 0] = cq.x;
        sacc[lq * 4 + 1] = cq.y;
        sacc[lq * 4 + 2] = cq.z;
        sacc[lq * 4 + 3] = cq.w;
    }

#pragma unroll
    for (int f = 0; f < F; ++f) {
        float v = fi[f];
        float v2 = v * v;
#pragma unroll
        for (int lq = 0; lq < L / 4; ++lq) {
            f32x4 Aq = *(const f32x4*)&s_A[f * L + lq * 4];
            f32x4 Bq = *(const f32x4*)&s_B[f * L + lq * 4];
            sacc[lq * 4 + 0] = fmaf(Aq.x, v2, fmaf(Bq.x, v, sacc[lq * 4 + 0]));
            sacc[lq * 4 + 1] = fmaf(Aq.y, v2, fmaf(Bq.y, v, sacc[lq * 4 + 1]));
            sacc[lq * 4 + 2] = fmaf(Aq.z, v2, fmaf(Bq.z, v, sacc[lq * 4 + 2]));
            sacc[lq * 4 + 3] = fmaf(Aq.w, v2, fmaf(Bq.w, v, sacc[lq * 4 + 3]));
        }
    }

    // ---- firing + normalization -> LDS ----
    float tot = 0.0f;
#pragma unroll
    for (int l = 0; l < L; ++l) {
        float fr = __builtin_amdgcn_exp2f(sacc[l]) + 0.001f;
        sacc[l] = fr;
        tot += fr;
    }
    float inv = __builtin_amdgcn_rcpf(tot);
#pragma unroll
    for (int l = 0; l < L; ++l) {
        float nl = sacc[l] * inv;
        sacc[l] = nl;                    // keep norm for consequents
        s_norm[l][tid] = nl;
    }

    // ---- consequents: w via wave-uniform global loads -> LDS ----
    float acc[YN] = {0.f, 0.f, 0.f, 0.f};
#pragma unroll
    for (int l = 0; l < L; ++l) {
        float t0 = 0.f, t1 = 0.f, t2 = 0.f, t3 = 0.f;
#pragma unroll
        for (int i = 0; i < XN; ++i) {
            f32x4 wq = *(const f32x4*)&w[(l * XN + i) * YN];  // uniform addr
            float xs = xv[i];
            t0 = fmaf(xs, wq.x, t0);
            t1 = fmaf(xs, wq.y, t1);
            t2 = fmaf(xs, wq.z, t2);
            t3 = fmaf(xs, wq.w, t3);
        }
        float nl = sacc[l];
        acc[0] = fmaf(nl, t0, acc[0]);
        acc[1] = fmaf(nl, t1, acc[1]);
        acc[2] = fmaf(nl, t2, acc[2]);
        acc[3] = fmaf(nl, t3, acc[3]);
    }
#pragma unroll
    for (int y = 0; y < YN; ++y) s_y[y][tid] = acc[y];

    __syncthreads();

    // ---- store phase: 16B/lane NT stores, 4 KB contiguous per wave-store ----
    const int ww = tid >> 6, lane = tid & 63;
    const size_t nidx = base_n + (size_t)lane * 4;
    const bool qok = (nidx + 3) < (size_t)n_total;   // n_total%4==0 -> exact guard

#pragma unroll
    for (int rr = 0; rr < 4; ++rr) {
        int row = ww * 4 + rr;
        f32x4 v = *(const f32x4*)&s_norm[row][lane * 4];
        if (qok)
            __builtin_nontemporal_store(v, (f32x4*)&out[(size_t)row * n_total + nidx]);
    }
    {
        f32x4 v = *(const f32x4*)&s_y[ww][lane * 4];   // ww < 4 == YN
        float* out_y = out + (size_t)L * n_total;
        if (qok)
            __builtin_nontemporal_store(v, (f32x4*)&out_y[(size_t)ww * n_total + nidx]);
    }
}

extern "C" void kernel_launch(void* const* d_in, const int* in_sizes, int n_in,
                              void* d_out, int out_size, void* d_ws, size_t ws_size,
                              hipStream_t stream) {
    const float* inp = (const float*)d_in[0];
    const float* x   = (const float*)d_in[1];
    const float* c   = (const float*)d_in[2];
    const float* b   = (const float*)d_in[3];
    const float* w   = (const float*)d_in[4];
    float* out = (float*)d_out;

    int n_total = in_sizes[0] / F;   // 500000
    int grid = (n_total + BLK - 1) / BLK;
    eafnn_kernel<<<grid, BLK, 0, stream>>>(inp, x, c, b, w, out, n_total, grid);
}